// Round 2
// baseline (2792.783 us; speedup 1.0000x reference)
//
#include <hip/hip_runtime.h>

// ---------------------------------------------------------------------------
// EquilibriumAgg: 10 steps of y <- y - 0.1 * grad_y E(y), E = sum over graphs
// of sum_n mean(potential([x_n, y])^2) + REG*mean(y^2).
// potential = LN(tanh(. W1+b1)) -> LN(tanh(. W2+b2)) -> . W3+b3
// Analytic backward; all matmuls via mfma_f32_16x16x32_bf16 (f32 accum).
// ---------------------------------------------------------------------------

typedef __attribute__((ext_vector_type(8))) short s8v;   // 8 x bf16
typedef __attribute__((ext_vector_type(4))) float f4v;   // mfma accumulator

// ws byte offsets
#define OFF_W1T 0          // [128][264] bf16 : W1T[n][k] = W1[k][n]        (fwd L1 B)
#define OFF_W1Y 67584      // [128][136] bf16 : W1Y[n][k] = W1[128+n][k]    (bwd dz B)
#define OFF_W2T 102400     // 16 frags * 512 bf16 (fwd L2 B)
#define OFF_W2B 118784     // 16 frags            (bwd dh1 B)
#define OFF_W3T 135168     // 2 frags             (fwd L3 B, cols>=10 zero)
#define OFF_W3B 137216     // 4 frags             (bwd dh2 B, k>=10 zero)
#define OFF_YBF 141312     // [512][128] bf16
#define OFF_YF  272384     // [512][128] f32
// total 534528 bytes of ws used

static __device__ __forceinline__ unsigned short f2b(float f){
  unsigned u = __float_as_uint(f);
  u = u + 0x7FFFu + ((u >> 16) & 1u);           // round-to-nearest-even
  return (unsigned short)(u >> 16);
}
static __device__ __forceinline__ float ftanh(float a){
  float e = __expf(2.0f * a);
  return 1.0f - __fdividef(2.0f, e + 1.0f);     // handles +-inf correctly
}
static __device__ __forceinline__ float rsum16(float v){
  v += __shfl_xor(v, 1); v += __shfl_xor(v, 2);
  v += __shfl_xor(v, 4); v += __shfl_xor(v, 8);
  return v;
}
static __device__ __forceinline__ f4v mfma16(s8v a, s8v b, f4v c){
  return __builtin_amdgcn_mfma_f32_16x16x32_bf16(a, b, c, 0, 0, 0);
}

// ---------------------------------------------------------------------------
__global__ void prep_kernel(const float* __restrict__ W1, const float* __restrict__ W2,
                            const float* __restrict__ W3, char* __restrict__ ws){
  int tid = blockIdx.x * blockDim.x + threadIdx.x;
  int nt = gridDim.x * blockDim.x;
  unsigned short* w1t = (unsigned short*)(ws + OFF_W1T);
  for (int idx = tid; idx < 128 * 256; idx += nt){
    int n = idx >> 8, k = idx & 255;
    w1t[n * 264 + k] = f2b(W1[k * 128 + n]);
  }
  unsigned short* w1y = (unsigned short*)(ws + OFF_W1Y);
  for (int idx = tid; idx < 128 * 128; idx += nt){
    int n = idx >> 7, k = idx & 127;
    w1y[n * 136 + k] = f2b(W1[(128 + n) * 128 + k]);
  }
  unsigned short* w2t = (unsigned short*)(ws + OFF_W2T);
  for (int idx = tid; idx < 16 * 512; idx += nt){
    int f = idx >> 9, pos = idx & 511, l = pos >> 3, j = pos & 7;
    int ntile = f >> 2, kt = f & 3;
    int n = ntile * 16 + (l & 15), k = kt * 32 + (l >> 4) * 8 + j;
    w2t[idx] = f2b(W2[k * 64 + n]);
  }
  unsigned short* w2b = (unsigned short*)(ws + OFF_W2B);
  for (int idx = tid; idx < 16 * 512; idx += nt){
    int f = idx >> 9, pos = idx & 511, l = pos >> 3, j = pos & 7;
    int ntile = f >> 1, kt = f & 1;
    int n = ntile * 16 + (l & 15), k = kt * 32 + (l >> 4) * 8 + j;
    w2b[idx] = f2b(W2[n * 64 + k]);
  }
  unsigned short* w3t = (unsigned short*)(ws + OFF_W3T);
  for (int idx = tid; idx < 2 * 512; idx += nt){
    int f = idx >> 9, pos = idx & 511, l = pos >> 3, j = pos & 7;
    int n = (l & 15), k = f * 32 + (l >> 4) * 8 + j;      // k < 64
    w3t[idx] = (n < 10) ? f2b(W3[k * 10 + n]) : (unsigned short)0;
  }
  unsigned short* w3b = (unsigned short*)(ws + OFF_W3B);
  for (int idx = tid; idx < 4 * 512; idx += nt){
    int f = idx >> 9, pos = idx & 511, l = pos >> 3, j = pos & 7;
    int n = f * 16 + (l & 15), k = (l >> 4) * 8 + j;      // k < 32
    w3b[idx] = (k < 10) ? f2b(W3[n * 10 + k]) : (unsigned short)0;
  }
}

// ---------------------------------------------------------------------------
struct __align__(16) SMem {
  unsigned short w1t[128 * 264];   // 67584 B
  unsigned short w1y[128 * 136];   // 34816 B
  unsigned short buf1[64 * 136];   // h1 -> dp([64][24]) -> da1
  unsigned short buf2[64 * 72];    // h2 -> da2
  float red_s[64][4];
  float red_q[64][4];
  unsigned short ybuf[128];
};                                  // 131328 B total

__launch_bounds__(512, 2)
__global__ void node_kernel(const float* __restrict__ x,
    const float* __restrict__ b1, const float* __restrict__ g1, const float* __restrict__ be1,
    const float* __restrict__ b2, const float* __restrict__ g2, const float* __restrict__ be2,
    const float* __restrict__ b3,
    const char* __restrict__ ws, float* __restrict__ grads_t){
  __shared__ SMem sm;
  const int tid = threadIdx.x;
  const int lane = tid & 63;
  const int w  = tid >> 6;
  const int wm = w >> 2;        // 0..1 : m-tile half
  const int wn = w & 3;         // 0..3 : n-tile quarter
  const int lg = lane >> 4;     // 0..3 : k-group
  const int lr = lane & 15;     // 0..15: A-row / B-col / C-col

  const unsigned short* w2t_g = (const unsigned short*)(ws + OFF_W2T);
  const unsigned short* w2b_g = (const unsigned short*)(ws + OFF_W2B);
  const unsigned short* w3t_g = (const unsigned short*)(ws + OFF_W3T);
  const unsigned short* w3b_g = (const unsigned short*)(ws + OFF_W3B);
  const unsigned short* ybf_g = (const unsigned short*)(ws + OFF_YBF);

  // stage W1T + W1Y (contiguous in ws and in LDS)
  {
    const uint4* src = (const uint4*)(ws + OFF_W1T);
    uint4* dst = (uint4*)&sm.w1t[0];
    #pragma unroll 1
    for (int i = tid; i < (67584 + 34816) / 16; i += 512) dst[i] = src[i];
  }

  const f4v z4 = {0.f, 0.f, 0.f, 0.f};
  const s8v z8 = {0, 0, 0, 0, 0, 0, 0, 0};

  #pragma unroll 1
  for (int c = blockIdx.x; c < 4096; c += gridDim.x){
    const int graph = c >> 3;
    const int node0 = c << 6;
    if (tid < 16) ((uint4*)sm.ybuf)[tid] = ((const uint4*)(ybf_g + graph * 128))[tid];
    __syncthreads();                                   // b0

    // ---- GEMM1: a1 = [x | y] @ W1   (M=64, K=256, N=128)
    f4v acc1[2][2];
    acc1[0][0]=z4; acc1[0][1]=z4; acc1[1][0]=z4; acc1[1][1]=z4;
    #pragma unroll
    for (int kt = 0; kt < 8; ++kt){
      s8v af[2];
      if (kt < 4){
        #pragma unroll
        for (int i = 0; i < 2; ++i){
          const float* p = x + (size_t)(node0 + (wm*2+i)*16 + lr) * 128 + kt*32 + lg*8;
          float4 f0 = *(const float4*)p;
          float4 f1 = *(const float4*)(p + 4);
          s8v t;
          t[0]=(short)f2b(f0.x); t[1]=(short)f2b(f0.y); t[2]=(short)f2b(f0.z); t[3]=(short)f2b(f0.w);
          t[4]=(short)f2b(f1.x); t[5]=(short)f2b(f1.y); t[6]=(short)f2b(f1.z); t[7]=(short)f2b(f1.w);
          af[i] = t;
        }
      } else {
        s8v t = *(const s8v*)&sm.ybuf[(kt-4)*32 + lg*8];
        af[0] = t; af[1] = t;
      }
      #pragma unroll
      for (int jn = 0; jn < 2; ++jn){
        s8v bf = *(const s8v*)&sm.w1t[((wn*2+jn)*16 + lr)*264 + kt*32 + lg*8];
        #pragma unroll
        for (int i = 0; i < 2; ++i)
          acc1[i][jn] = mfma16(af[i], bf, acc1[i][jn]);
      }
    }

    // ---- EW1: tanh + LN1 (D=128); save xh1/dd1/sig1; h1 -> buf1
    float tv[2][2][4], xh1[2][2][4], dd1[2][2][4], sig1[2][4];
    #pragma unroll
    for (int i = 0; i < 2; ++i)
      #pragma unroll
      for (int jn = 0; jn < 2; ++jn){
        float bb = b1[wn*32 + jn*16 + lr];
        #pragma unroll
        for (int r = 0; r < 4; ++r)
          tv[i][jn][r] = ftanh(acc1[i][jn][r] + bb);
      }
    #pragma unroll
    for (int i = 0; i < 2; ++i)
      #pragma unroll
      for (int r = 0; r < 4; ++r){
        float s = tv[i][0][r] + tv[i][1][r];
        float q = tv[i][0][r]*tv[i][0][r] + tv[i][1][r]*tv[i][1][r];
        s = rsum16(s); q = rsum16(q);
        if (lr == 0){
          int row = (wm*2+i)*16 + lg*4 + r;
          sm.red_s[row][wn] = s; sm.red_q[row][wn] = q;
        }
      }
    __syncthreads();                                   // b1
    #pragma unroll
    for (int i = 0; i < 2; ++i)
      #pragma unroll
      for (int r = 0; r < 4; ++r){
        int row = (wm*2+i)*16 + lg*4 + r;
        float4 ss = *(const float4*)&sm.red_s[row][0];
        float4 qq = *(const float4*)&sm.red_q[row][0];
        float S = (ss.x + ss.y) + (ss.z + ss.w);
        float Q = (qq.x + qq.y) + (qq.z + qq.w);
        float mu  = S * (1.0f/128.0f);
        float var = Q * (1.0f/128.0f) - mu*mu;
        float sg  = rsqrtf(var + 1e-5f);
        sig1[i][r] = sg;
        #pragma unroll
        for (int jn = 0; jn < 2; ++jn){
          int col = wn*32 + jn*16 + lr;
          float tt = tv[i][jn][r];
          float xh = (tt - mu) * sg;
          xh1[i][jn][r] = xh;
          dd1[i][jn][r] = 1.0f - tt*tt;
          sm.buf1[row*136 + col] = f2b(xh * g1[col] + be1[col]);
        }
      }
    __syncthreads();                                   // b2

    // ---- GEMM2: a2 = h1 @ W2   (M=64, K=128, N=64)
    f4v acc2[2]; acc2[0]=z4; acc2[1]=z4;
    #pragma unroll
    for (int kt = 0; kt < 4; ++kt){
      s8v bf = *(const s8v*)(w2t_g + ((wn*4 + kt)*64 + lane)*8);
      #pragma unroll
      for (int i = 0; i < 2; ++i){
        s8v af = *(const s8v*)&sm.buf1[((wm*2+i)*16 + lr)*136 + kt*32 + lg*8];
        acc2[i] = mfma16(af, bf, acc2[i]);
      }
    }
    // ---- EW2: tanh + LN2 (D=64); save xh2/dd2/sig2; h2 -> buf2
    float t2[2][4], xh2[2][4], dd2[2][4], sig2[2][4];
    {
      const int col2 = wn*16 + lr;
      float bb = b2[col2];
      #pragma unroll
      for (int i = 0; i < 2; ++i)
        #pragma unroll
        for (int r = 0; r < 4; ++r)
          t2[i][r] = ftanh(acc2[i][r] + bb);
      #pragma unroll
      for (int i = 0; i < 2; ++i)
        #pragma unroll
        for (int r = 0; r < 4; ++r){
          float s = rsum16(t2[i][r]);
          float q = rsum16(t2[i][r]*t2[i][r]);
          if (lr == 0){
            int row = (wm*2+i)*16 + lg*4 + r;
            sm.red_s[row][wn] = s; sm.red_q[row][wn] = q;
          }
        }
      __syncthreads();                                 // b3
      #pragma unroll
      for (int i = 0; i < 2; ++i)
        #pragma unroll
        for (int r = 0; r < 4; ++r){
          int row = (wm*2+i)*16 + lg*4 + r;
          float4 ss = *(const float4*)&sm.red_s[row][0];
          float4 qq = *(const float4*)&sm.red_q[row][0];
          float S = (ss.x+ss.y)+(ss.z+ss.w);
          float Q = (qq.x+qq.y)+(qq.z+qq.w);
          float mu  = S * (1.0f/64.0f);
          float var = Q * (1.0f/64.0f) - mu*mu;
          float sg  = rsqrtf(var + 1e-5f);
          sig2[i][r] = sg;
          float tt = t2[i][r];
          float xh = (tt - mu) * sg;
          xh2[i][r] = xh; dd2[i][r] = 1.0f - tt*tt;
          sm.buf2[row*72 + col2] = f2b(xh * g2[col2] + be2[col2]);
        }
      __syncthreads();                                 // b4
    }

    // ---- GEMM3 + dp (wn==0 waves only; N padded to 16, cols>=10 are zero)
    if (wn == 0){
      f4v acc3[2]; acc3[0]=z4; acc3[1]=z4;
      #pragma unroll
      for (int kt = 0; kt < 2; ++kt){
        s8v bf = *(const s8v*)(w3t_g + (kt*64 + lane)*8);
        #pragma unroll
        for (int i = 0; i < 2; ++i){
          s8v af = *(const s8v*)&sm.buf2[((wm*2+i)*16 + lr)*72 + kt*32 + lg*8];
          acc3[i] = mfma16(af, bf, acc3[i]);
        }
      }
      float bb3 = (lr < 10) ? b3[lr] : 0.0f;
      #pragma unroll
      for (int i = 0; i < 2; ++i)
        #pragma unroll
        for (int r = 0; r < 4; ++r){
          int row = (wm*2+i)*16 + lg*4 + r;
          float p = acc3[i][r] + bb3;
          sm.buf1[row*24 + lr] = (lr < 10) ? f2b(0.2f * p) : (unsigned short)0;  // dp = (2/10) p
        }
    }
    __syncthreads();                                   // b5

    // ---- GEMM b3: dh2 = dp @ W3^T   (M=64, K=16(pad32), N=64)
    f4v accb3[2]; accb3[0]=z4; accb3[1]=z4;
    {
      s8v bf = *(const s8v*)(w3b_g + (wn*64 + lane)*8);
      #pragma unroll
      for (int i = 0; i < 2; ++i){
        s8v af = z8;
        if (lg < 2) af = *(const s8v*)&sm.buf1[((wm*2+i)*16 + lr)*24 + lg*8];
        accb3[i] = mfma16(af, bf, accb3[i]);
      }
    }
    // ---- EWb2: LN2 backward + tanh'; da2 -> buf2
    {
      const int col2 = wn*16 + lr;
      float gg = g2[col2];
      float dyv2[2][4];
      #pragma unroll
      for (int i = 0; i < 2; ++i)
        #pragma unroll
        for (int r = 0; r < 4; ++r){
          float dy = accb3[i][r] * gg;
          dyv2[i][r] = dy;
          float s1 = rsum16(dy);
          float s2 = rsum16(dy * xh2[i][r]);
          if (lr == 0){
            int row = (wm*2+i)*16 + lg*4 + r;
            sm.red_s[row][wn] = s1; sm.red_q[row][wn] = s2;
          }
        }
      __syncthreads();                                 // b6
      #pragma unroll
      for (int i = 0; i < 2; ++i)
        #pragma unroll
        for (int r = 0; r < 4; ++r){
          int row = (wm*2+i)*16 + lg*4 + r;
          float4 ss = *(const float4*)&sm.red_s[row][0];
          float4 qq = *(const float4*)&sm.red_q[row][0];
          float S1 = (ss.x+ss.y)+(ss.z+ss.w);
          float S2 = (qq.x+qq.y)+(qq.z+qq.w);
          float dt = sig2[i][r] * (dyv2[i][r] - S1*(1.0f/64.0f) - xh2[i][r]*S2*(1.0f/64.0f));
          sm.buf2[row*72 + col2] = f2b(dt * dd2[i][r]);
        }
      __syncthreads();                                 // b7
    }

    // ---- GEMM b2: dh1 = da2 @ W2^T   (M=64, K=64, N=128)
    f4v accb2[2][2];
    accb2[0][0]=z4; accb2[0][1]=z4; accb2[1][0]=z4; accb2[1][1]=z4;
    #pragma unroll
    for (int kt = 0; kt < 2; ++kt){
      s8v af[2];
      #pragma unroll
      for (int i = 0; i < 2; ++i)
        af[i] = *(const s8v*)&sm.buf2[((wm*2+i)*16 + lr)*72 + kt*32 + lg*8];
      #pragma unroll
      for (int jn = 0; jn < 2; ++jn){
        s8v bf = *(const s8v*)(w2b_g + (((wn*2+jn)*2 + kt)*64 + lane)*8);
        #pragma unroll
        for (int i = 0; i < 2; ++i)
          accb2[i][jn] = mfma16(af[i], bf, accb2[i][jn]);
      }
    }
    // ---- EWb1: LN1 backward + tanh'; da1 -> buf1
    {
      float dyv[2][2][4];
      #pragma unroll
      for (int i = 0; i < 2; ++i)
        #pragma unroll
        for (int jn = 0; jn < 2; ++jn){
          float gg = g1[wn*32 + jn*16 + lr];
          #pragma unroll
          for (int r = 0; r < 4; ++r)
            dyv[i][jn][r] = accb2[i][jn][r] * gg;
        }
      #pragma unroll
      for (int i = 0; i < 2; ++i)
        #pragma unroll
        for (int r = 0; r < 4; ++r){
          float s1 = dyv[i][0][r] + dyv[i][1][r];
          float s2 = dyv[i][0][r]*xh1[i][0][r] + dyv[i][1][r]*xh1[i][1][r];
          s1 = rsum16(s1); s2 = rsum16(s2);
          if (lr == 0){
            int row = (wm*2+i)*16 + lg*4 + r;
            sm.red_s[row][wn] = s1; sm.red_q[row][wn] = s2;
          }
        }
      __syncthreads();                                 // b8
      #pragma unroll
      for (int i = 0; i < 2; ++i)
        #pragma unroll
        for (int r = 0; r < 4; ++r){
          int row = (wm*2+i)*16 + lg*4 + r;
          float4 ss = *(const float4*)&sm.red_s[row][0];
          float4 qq = *(const float4*)&sm.red_q[row][0];
          float S1 = (ss.x+ss.y)+(ss.z+ss.w);
          float S2 = (qq.x+qq.y)+(qq.z+qq.w);
          #pragma unroll
          for (int jn = 0; jn < 2; ++jn){
            int col = wn*32 + jn*16 + lr;
            float dt = sig1[i][r]*(dyv[i][jn][r] - S1*(1.0f/128.0f) - xh1[i][jn][r]*S2*(1.0f/128.0f));
            sm.buf1[row*136 + col] = f2b(dt * dd1[i][jn][r]);
          }
        }
      __syncthreads();                                 // b9
    }

    // ---- GEMM bz: dz_y = da1 @ W1[y-half]^T   (M=64, K=128, N=128)
    f4v accz[2][2];
    accz[0][0]=z4; accz[0][1]=z4; accz[1][0]=z4; accz[1][1]=z4;
    #pragma unroll
    for (int kt = 0; kt < 4; ++kt){
      s8v af[2];
      #pragma unroll
      for (int i = 0; i < 2; ++i)
        af[i] = *(const s8v*)&sm.buf1[((wm*2+i)*16 + lr)*136 + kt*32 + lg*8];
      #pragma unroll
      for (int jn = 0; jn < 2; ++jn){
        s8v bf = *(const s8v*)&sm.w1y[((wn*2+jn)*16 + lr)*136 + kt*32 + lg*8];
        #pragma unroll
        for (int i = 0; i < 2; ++i)
          accz[i][jn] = mfma16(af[i], bf, accz[i][jn]);
      }
    }
    // column-sum over the wave's 32 rows, then one atomicAdd per column
    #pragma unroll
    for (int jn = 0; jn < 2; ++jn){
      float s = ((accz[0][jn][0] + accz[0][jn][1]) + (accz[0][jn][2] + accz[0][jn][3]))
              + ((accz[1][jn][0] + accz[1][jn][1]) + (accz[1][jn][2] + accz[1][jn][3]));
      s += __shfl_xor(s, 16);
      s += __shfl_xor(s, 32);
      if (lg == 0)
        atomicAdd(&grads_t[graph*128 + wn*32 + jn*16 + lr], s);
    }
  }
}

// ---------------------------------------------------------------------------
__global__ void update_kernel(char* __restrict__ ws, float* __restrict__ dout, int t){
  int idx = blockIdx.x * blockDim.x + threadIdx.x;   // 65536 threads
  float* gr = dout + 65536 + t * 65536;
  float* y  = (float*)(ws + OFF_YF);
  unsigned short* yb = (unsigned short*)(ws + OFF_YBF);
  float g = gr[idx] + 1.5625e-5f * y[idx];           // + (2*REG/128) * y
  gr[idx] = g;
  float yn = y[idx] - 0.1f * g;
  y[idx] = yn;
  yb[idx] = f2b(yn);
  if (t == 9) dout[idx] = yn;                        // yT
}

// ---------------------------------------------------------------------------
extern "C" void kernel_launch(void* const* d_in, const int* in_sizes, int n_in,
                              void* d_out, int out_size, void* d_ws, size_t ws_size,
                              hipStream_t stream){
  const float* x   = (const float*)d_in[0];
  // d_in[1] = batch (unused; equal-size graphs)
  const float* W1  = (const float*)d_in[2];
  const float* b1  = (const float*)d_in[3];
  const float* g1  = (const float*)d_in[4];
  const float* be1 = (const float*)d_in[5];
  const float* W2  = (const float*)d_in[6];
  const float* b2  = (const float*)d_in[7];
  const float* g2  = (const float*)d_in[8];
  const float* be2 = (const float*)d_in[9];
  const float* W3  = (const float*)d_in[10];
  const float* b3  = (const float*)d_in[11];
  float* out = (float*)d_out;
  char* ws = (char*)d_ws;

  // zero y (f32 + bf16) and the grads region of d_out
  hipMemsetAsync(ws + OFF_YBF, 0, 131072 + 262144, stream);
  hipMemsetAsync(out + 65536, 0, 10 * 65536 * sizeof(float), stream);

  prep_kernel<<<64, 256, 0, stream>>>(W1, W2, W3, ws);

  for (int t = 0; t < 10; ++t){
    node_kernel<<<256, 512, 0, stream>>>(x, b1, g1, be1, b2, g2, be2, b3,
                                         (const char*)ws, out + 65536 + t * 65536);
    update_kernel<<<256, 256, 0, stream>>>(ws, out, t);
  }
}